// Round 3
// baseline (488.631 us; speedup 1.0000x reference)
//
#include <hip/hip_runtime.h>
#include <hip/hip_bf16.h>
#include <stdint.h>

typedef __hip_bfloat16 bf16;
typedef __attribute__((ext_vector_type(8))) short bf16x8;   // 8 bf16 = 4 VGPRs (MFMA A/B frag)
typedef __attribute__((ext_vector_type(4))) float f32x4;    // MFMA C/D frag + 16B loads
typedef __attribute__((ext_vector_type(4))) short s16x4;    // 8B bf16 store

constexpr int D_MODEL   = 2048;
constexpr int NUM_HEADS = 16;
constexpr int HEAD_DIM  = 128;
constexpr int BATCH     = 2;
constexpr int SEQ       = 2048;

// GEMM tile geometry (shared by all GEMM kernels)
constexpr int GBM = 256, GBN = 128, GBK = 64;
constexpr int G_ABUF = GBM * GBK;            // 16384 elems (32 KB)
constexpr int G_BBUF = GBN * GBK;            // 8192  elems (16 KB)
constexpr int G_BUF  = G_ABUF + G_BBUF;      // 24576 elems (48 KB)
constexpr int G_LDS  = 3 * G_BUF;            // 73728 elems (144 KB)

// async global->LDS, 16B per lane; LDS dest must be wave-uniform base + lane*16
__device__ __forceinline__ void gload_lds16(const bf16* g, bf16* l) {
    __builtin_amdgcn_global_load_lds(
        (const __attribute__((address_space(1))) void*)g,
        (__attribute__((address_space(3))) void*)l, 16, 0, 0);
}

// ---------------------------------------------------------------------------
// fp32 -> bf16 bulk convert, up to 7 tensors in one launch (blockIdx.y selects)
// ---------------------------------------------------------------------------
struct CvtArgs { const float* src[7]; bf16* dst[7]; int n8[7]; };

__global__ __launch_bounds__(256)
void cvt_multi(CvtArgs a)
{
    const int t = blockIdx.y;
    const float* __restrict__ s = a.src[t];
    bf16* __restrict__ d = a.dst[t];
    const int n8 = a.n8[t];
    for (int i = blockIdx.x * 256 + threadIdx.x; i < n8; i += gridDim.x * 256) {
        f32x4 x = *(const f32x4*)(s + (size_t)i * 8);
        f32x4 y = *(const f32x4*)(s + (size_t)i * 8 + 4);
        bf16 t8[8] = { __float2bfloat16(x[0]), __float2bfloat16(x[1]),
                       __float2bfloat16(x[2]), __float2bfloat16(x[3]),
                       __float2bfloat16(y[0]), __float2bfloat16(y[1]),
                       __float2bfloat16(y[2]), __float2bfloat16(y[3]) };
        *(bf16x8*)(d + (size_t)i * 8) = *(const bf16x8*)t8;
    }
}

// ---------------------------------------------------------------------------
// GEMM core, 8-phase schedule (T2+T3+T4+T5): C[M,N] = A[M,K] @ W[N,K]^T + bias
// BM=256 x BN=128, BK=64, 8 waves (4Mx2N, 64x64 per wave), 512 threads.
// Triple-buffered LDS (3 x 48KB = 144KB, 1 block/CU), counted vmcnt(6) only at
// tile boundaries (never 0 in steady state), raw s_barrier (no drain),
// XOR-swizzled LDS: chunk g of row stored at slot g^(row&7) (pre-swizzled
// global source, linear gload_lds dest, swizzled ds_read — both-sides rule).
// Triangle MFMA split: phase p computes {(i,j): max(i,j)=p}, every A/B frag
// ds_read exactly once per K-tile (keeps LDS BW under the MFMA time).
// NOTE: the __shared__ buffer lives in the __global__ wrapper (declared ONCE)
// and is passed in — two instantiations inside one kernel must SHARE it, or
// static LDS doubles to 288KB and compilation fails (round-2 lesson).
// ---------------------------------------------------------------------------
template <int P>
__device__ __forceinline__
void phase_mfma(f32x4 (&acc)[4][4], bf16x8 (&a)[4][2], bf16x8 (&b)[4][2])
{
#pragma unroll
    for (int kk = 0; kk < 2; kk++) {
#pragma unroll
        for (int j = 0; j <= P; j++)
            acc[P][j] = __builtin_amdgcn_mfma_f32_16x16x32_bf16(a[P][kk], b[j][kk], acc[P][j], 0, 0, 0);
#pragma unroll
        for (int i = 0; i < P; i++)
            acc[i][P] = __builtin_amdgcn_mfma_f32_16x16x32_bf16(a[i][kk], b[P][kk], acc[i][P], 0, 0, 0);
    }
}

template <typename TC, bool TRANS_PERM>
__device__ __forceinline__
void gemm_body(const bf16* __restrict__ A, const bf16* __restrict__ W,
               const float* __restrict__ bias, TC* __restrict__ C,
               int M, int N, int K, bf16* smem)
{
    const int tid  = threadIdx.x;
    const int lane = tid & 63;
    const int wave = tid >> 6;               // 0..7
    const int quad = lane >> 4, l16 = lane & 15;
    const int sw   = l16 & 7;
    const int wr   = wave >> 1;              // 0..3 : M direction, 64 rows
    const int wc   = wave & 1;               // 0..1 : N direction, 64 cols
    const int m0   = blockIdx.y * GBM, n0 = blockIdx.x * GBN;

    // staging thread-invariants: chunk c = u*512 + tid; row = u*64 + (tid>>3),
    // slot = tid&7, fetched global chunk g = slot ^ (row&7)  (involution)
    const int rloc = tid >> 3;               // 0..63
    const int gsw  = (tid & 7) ^ (rloc & 7);
    const int NT   = K / GBK;

    const bf16* Abase = A + (size_t)(m0 + rloc) * K + gsw * 8;
    const bf16* Bbase = W + (size_t)(n0 + rloc) * K + gsw * 8;
    const size_t rstep = (size_t)64 * K;

    auto stageA = [&](int t, int bi, int u) {
        gload_lds16(Abase + u * rstep + (size_t)t * GBK,
                    smem + bi * G_BUF + (u * 512 + tid) * 8);
    };
    auto stageB = [&](int t, int bi, int u) {
        gload_lds16(Bbase + u * rstep + (size_t)t * GBK,
                    smem + bi * G_BUF + G_ABUF + (u * 512 + tid) * 8);
    };

    f32x4 acc[4][4];
#pragma unroll
    for (int i = 0; i < 4; i++)
#pragma unroll
        for (int j = 0; j < 4; j++) acc[i][j] = (f32x4){0.f, 0.f, 0.f, 0.f};

    bf16x8 a[4][2], b[4][2];

    // prologue: stage tiles 0 and 1 (12 loads/thread in flight)
#pragma unroll
    for (int u = 0; u < 4; u++) stageA(0, 0, u);
#pragma unroll
    for (int u = 0; u < 2; u++) stageB(0, 0, u);
    if (NT > 1) {
#pragma unroll
        for (int u = 0; u < 4; u++) stageA(1, 1, u);
#pragma unroll
        for (int u = 0; u < 2; u++) stageB(1, 1, u);
        asm volatile("s_waitcnt vmcnt(6)" ::: "memory");   // tile 0 landed
    } else {
        asm volatile("s_waitcnt vmcnt(0)" ::: "memory");
    }
    asm volatile("s_barrier" ::: "memory");

// phase p: issue next-next-tile stage loads, ds_read this phase's frags,
// barrier, setprio(1), MFMA triangle slice, setprio(0). Trailing barrier
// placed by caller (tile boundary adds the counted vmcnt before it).
#define GEMM_PHASE(p, STAGE_STMT)                                              \
    {                                                                          \
        STAGE_STMT;                                                            \
        const int rA = wr * 64 + (p) * 16 + l16;                               \
        const int rB = wc * 64 + (p) * 16 + l16;                               \
        a[p][0] = *(const bf16x8*)&sAc[rA * 64 + (quad ^ sw) * 8];             \
        a[p][1] = *(const bf16x8*)&sAc[rA * 64 + (((4 + quad) ^ sw)) * 8];     \
        b[p][0] = *(const bf16x8*)&sBc[rB * 64 + (quad ^ sw) * 8];             \
        b[p][1] = *(const bf16x8*)&sBc[rB * 64 + (((4 + quad) ^ sw)) * 8];     \
        __builtin_amdgcn_s_barrier();                                          \
        __builtin_amdgcn_s_setprio(1);                                         \
        phase_mfma<p>(acc, a, b);                                              \
        __builtin_amdgcn_s_setprio(0);                                         \
    }

    int bc = 0;                              // buffer holding tile t
    for (int t = 0; t < NT; ++t) {
        const bf16* sAc = smem + bc * G_BUF;
        const bf16* sBc = sAc + G_ABUF;
        const int bs = (bc + 2 >= 3) ? bc - 1 : bc + 2;   // buffer for tile t+2
        const bool pf = (t + 2 < NT);

        GEMM_PHASE(0, if (pf) { stageA(t + 2, bs, 0); stageA(t + 2, bs, 1); })
        __builtin_amdgcn_s_barrier();
        GEMM_PHASE(1, if (pf) { stageA(t + 2, bs, 2); stageA(t + 2, bs, 3); })
        __builtin_amdgcn_s_barrier();
        GEMM_PHASE(2, if (pf) { stageB(t + 2, bs, 0); })
        __builtin_amdgcn_s_barrier();
        GEMM_PHASE(3, if (pf) { stageB(t + 2, bs, 1); })
        // tile boundary: own-wave counted wait, then collective barrier.
        // vmcnt(6) leaves exactly tile t+2's 6 loads in flight => tile t+1's
        // LDS writes have landed for every wave after the barrier.
        if (pf)                asm volatile("s_waitcnt vmcnt(6)" ::: "memory");
        else if (t + 1 < NT)   asm volatile("s_waitcnt vmcnt(0)" ::: "memory");
        asm volatile("s_barrier" ::: "memory");
        bc = (bc + 1 == 3) ? 0 : bc + 1;
    }
#undef GEMM_PHASE

    // epilogue: C/D layout col=lane&15 (B-frag row), row=quad*4+reg (A-frag row)
#pragma unroll
    for (int j = 0; j < 4; j++) {
        const int col = n0 + wc * 64 + j * 16 + l16;
        const float bv = bias[col];
#pragma unroll
        for (int i = 0; i < 4; i++) {
            const int row0 = m0 + wr * 64 + i * 16 + quad * 4;
            if constexpr (TRANS_PERM) {
                // V output: [b][h][dh][s'] with the flash key-permutation applied
                // within each 64-token group: pos p = c*32 + qh*8 + t*4 + r holds
                // key (2c+t)*16 + qh*4 + r.
                int g   = row0 & 63;                           // g & 3 == 0
                int tau = g >> 4, qh = (g >> 2) & 3;
                int pp  = (tau >> 1) * 32 + qh * 8 + (tau & 1) * 4;
                int sp  = ((row0 & 2047) & ~63) | pp;
                size_t idx = (size_t)(row0 >> 11) * ((size_t)D_MODEL * SEQ)
                           + (size_t)col * SEQ + sp;
                bf16 t4[4];
#pragma unroll
                for (int r = 0; r < 4; r++) t4[r] = __float2bfloat16(acc[i][j][r] + bv);
                *(s16x4*)&C[idx] = *(const s16x4*)t4;
            } else {
#pragma unroll
                for (int r = 0; r < 4; r++) {
                    int row = row0 + r;
                    if constexpr (sizeof(TC) == 2)
                        C[(size_t)row * N + col] = (TC)__float2bfloat16(acc[i][j][r] + bv);
                    else
                        C[(size_t)row * N + col] = (TC)(acc[i][j][r] + bv);
                }
            }
        }
    }
}

template <typename TC, bool TRANS_PERM>
__global__ __launch_bounds__(512, 1)
void gemm_bf16(const bf16* __restrict__ A, const bf16* __restrict__ W,
               const float* __restrict__ bias, TC* __restrict__ C,
               int M, int N, int K)
{
    __shared__ bf16 smem[G_LDS];
    gemm_body<TC, TRANS_PERM>(A, W, bias, C, M, N, K, smem);
}

// fused Q+K+V projections: blockIdx.z selects tensor; z==2 is V (trans+perm)
struct QkvArgs { const bf16* A[3]; const bf16* W[3]; const float* bias[3]; bf16* C[3]; };

__global__ __launch_bounds__(512, 1)
void gemm_qkv(QkvArgs ga, int M, int N, int K)
{
    __shared__ bf16 smem[G_LDS];             // ONE buffer, shared by both paths
    const int z = blockIdx.z;
    if (z == 2) gemm_body<bf16, true >(ga.A[2], ga.W[2], ga.bias[2], ga.C[2], M, N, K, smem);
    else        gemm_body<bf16, false>(ga.A[z], ga.W[z], ga.bias[z], ga.C[z], M, N, K, smem);
}

// fused Q+K only (fallback when ws is tight)
struct QkArgs { const bf16* A[2]; const bf16* W[2]; const float* bias[2]; bf16* C[2]; };

__global__ __launch_bounds__(512, 1)
void gemm_qk(QkArgs ga, int M, int N, int K)
{
    __shared__ bf16 smem[G_LDS];
    const int z = blockIdx.z;
    gemm_body<bf16, false>(ga.A[z], ga.W[z], ga.bias[z], ga.C[z], M, N, K, smem);
}

// ---------------------------------------------------------------------------
// Flash attention v3: operand-swapped (S^T/O^T), no-max softmax, P in regs,
// double-buffered async K/V staging (global_load_lds 16B, XOR-swizzled LDS),
// ONE barrier per K-tile iteration.  (unchanged this round)
// ---------------------------------------------------------------------------
__global__ __launch_bounds__(256)
void flash_attn_kernel(const bf16* __restrict__ Qp, const bf16* __restrict__ Kp,
                       const bf16* __restrict__ Vt, bf16* __restrict__ Op)
{
    constexpr int BQ = 128, BKV = 64, DH = 128;
    __shared__ bf16 sK[2][BKV * DH];       // 2 x 16 KB
    __shared__ bf16 sV[2][DH * BKV];       // 2 x 16 KB

    const int tid  = threadIdx.x;
    const int wave = tid >> 6, lane = tid & 63;
    const int quad = lane >> 4, l16 = lane & 15;
    const int q0 = blockIdx.x * BQ;
    const int h  = blockIdx.y;
    const int b  = blockIdx.z;

    const size_t base  = (size_t)b * SEQ * D_MODEL + (size_t)h * HEAD_DIM;
    const size_t basev = ((size_t)b * NUM_HEADS + h) * (size_t)HEAD_DIM * SEQ;
    const bf16* Kb = Kp + base;
    const bf16* Vb = Vt + basev;

    auto stage = [&](int t, int bi) {
        const bf16* Kt = Kb + (size_t)t * BKV * D_MODEL;
        const bf16* Vtile = Vb + (size_t)t * BKV;
        bf16* sKb = sK[bi];
        bf16* sVb = sV[bi];
#pragma unroll
        for (int s = 0; s < 4; s++) {
            int c = s * 256 + wave * 64 + lane;            // 0..1023
            int row = c >> 4, gs = c & 15;
            int g = gs ^ (row & 15);
            gload_lds16(Kt + (size_t)row * D_MODEL + g * 8, sKb + (size_t)c * 8);
        }
#pragma unroll
        for (int s = 0; s < 4; s++) {
            int c = s * 256 + wave * 64 + lane;            // 0..1023
            int dh = c >> 3, gs = c & 7;
            int g = gs ^ (dh & 7);
            gload_lds16(Vtile + (size_t)dh * SEQ + g * 8, sVb + (size_t)c * 8);
        }
    };

    bf16x8 bq[2][4];
#pragma unroll
    for (int nt = 0; nt < 2; nt++)
#pragma unroll
        for (int kk = 0; kk < 4; kk++)
            bq[nt][kk] = *(const bf16x8*)&Qp[base +
                (size_t)(q0 + wave * 32 + nt * 16 + l16) * D_MODEL + kk * 32 + quad * 8];

    f32x4 oacc[2][8];
#pragma unroll
    for (int nt = 0; nt < 2; nt++)
#pragma unroll
        for (int mt = 0; mt < 8; mt++) oacc[nt][mt] = (f32x4){0.f, 0.f, 0.f, 0.f};

    float lsum[2] = {0.f, 0.f};

    const float SCL2E = 0.08838834764831845f * 1.4426950408889634f;
    constexpr int NT = SEQ / BKV;          // 32

    stage(0, 0);

    for (int t = 0; t < NT; ++t) {
        __syncthreads();
        if (t + 1 < NT) stage(t + 1, (t + 1) & 1);

        const bf16* sKc = sK[t & 1];
        const bf16* sVc = sV[t & 1];

        f32x4 sacc[2][4];
#pragma unroll
        for (int nt = 0; nt < 2; nt++)
#pragma unroll
            for (int kt = 0; kt < 4; kt++) sacc[nt][kt] = (f32x4){0.f, 0.f, 0.f, 0.f};
#pragma unroll
        for (int kk = 0; kk < 4; kk++) {
            bf16x8 ak[4];
#pragma unroll
            for (int kt = 0; kt < 4; kt++) {
                int row = kt * 16 + l16;
                int g   = (kk * 4 + quad) ^ l16;
                ak[kt] = *(const bf16x8*)&sKc[(size_t)row * DH + g * 8];
            }
#pragma unroll
            for (int nt = 0; nt < 2; nt++)
#pragma unroll
                for (int kt = 0; kt < 4; kt++)
                    sacc[nt][kt] = __builtin_amdgcn_mfma_f32_16x16x32_bf16(ak[kt], bq[nt][kk], sacc[nt][kt], 0, 0, 0);
        }

        bf16x8 pb[2][2];
#pragma unroll
        for (int nt = 0; nt < 2; nt++) {
            bf16 tmp[16];
#pragma unroll
            for (int kt = 0; kt < 4; kt++) {
#pragma unroll
                for (int r = 0; r < 4; r++) {
                    float p = exp2f(fminf(sacc[nt][kt][r] * SCL2E, 60.f));
                    lsum[nt] += p;
                    tmp[(kt >> 1) * 8 + (kt & 1) * 4 + r] = __float2bfloat16(p);
                }
            }
            pb[nt][0] = *(const bf16x8*)&tmp[0];
            pb[nt][1] = *(const bf16x8*)&tmp[8];
        }

#pragma unroll
        for (int c = 0; c < 2; c++) {
#pragma unroll
            for (int mt = 0; mt < 8; mt++) {
                int row = mt * 16 + l16;
                int g   = (c * 4 + quad) ^ (l16 & 7);
                bf16x8 av = *(const bf16x8*)&sVc[(size_t)row * BKV + g * 8];
#pragma unroll
                for (int nt = 0; nt < 2; nt++)
                    oacc[nt][mt] = __builtin_amdgcn_mfma_f32_16x16x32_bf16(av, pb[nt][c], oacc[nt][mt], 0, 0, 0);
            }
        }
    }

#pragma unroll
    for (int nt = 0; nt < 2; nt++) {
        float v = lsum[nt];
        v += __shfl_xor(v, 16);
        v += __shfl_xor(v, 32);
        lsum[nt] = v;
    }

#pragma unroll
    for (int nt = 0; nt < 2; nt++) {
        float inv = 1.f / lsum[nt];
        int row = q0 + wave * 32 + nt * 16 + l16;
#pragma unroll
        for (int mt = 0; mt < 8; mt++) {
            bf16 t4[4];
#pragma unroll
            for (int r = 0; r < 4; r++) t4[r] = __float2bfloat16(oacc[nt][mt][r] * inv);
            *(s16x4*)&Op[base + (size_t)row * D_MODEL + mt * 16 + quad * 4] = *(const s16x4*)t4;
        }
    }
}

// ---------------------------------------------------------------------------
extern "C" void kernel_launch(void* const* d_in, const int* in_sizes, int n_in,
                              void* d_out, int out_size, void* d_ws, size_t ws_size,
                              hipStream_t stream)
{
    const float* query  = (const float*)d_in[0];
    const float* key_in = (const float*)d_in[1];
    const float* value  = (const float*)d_in[2];
    const float* Wq = (const float*)d_in[3];
    const float* bq = (const float*)d_in[4];
    const float* Wk = (const float*)d_in[5];
    const float* bk = (const float*)d_in[6];
    const float* Wv = (const float*)d_in[7];
    const float* bv = (const float*)d_in[8];
    const float* Wo = (const float*)d_in[9];
    const float* bo = (const float*)d_in[10];
    float* out = (float*)d_out;

    const int tokens = BATCH * SEQ;                          // 4096
    const size_t nAct = (size_t)tokens * D_MODEL;            // 8.4M elems
    const size_t nW   = (size_t)D_MODEL * D_MODEL;           // 4.2M elems

    const bool fused_qkv = ws_size >= (6 * nAct + 4 * nW) * sizeof(bf16);

    bf16* p = (bf16*)d_ws;
    bf16* qb  = p; p += nAct;      // bf16 activations
    bf16* kb  = p; p += nAct;
    bf16* vb  = p; p += nAct;
    bf16* wqb = p; p += nW;        // bf16 weights
    bf16* wkb = p; p += nW;
    bf16* wvb = p; p += nW;
    bf16* wob = p; p += nW;
    bf16* qp  = p; p += nAct;      // Q,K projections
    bf16* kp  = p; p += nAct;
    bf16* vpT;                     // V projection (transposed+permuted)
    if (fused_qkv) { vpT = p; p += nAct; }
    else           { vpT = qb; }   // fallback: alias (QK launch consumes qb first)
    bf16* ap = fused_qkv ? qb : kb; // attn out: aliases an activation consumed earlier

    // 1. fp32 -> bf16 (one launch)
    CvtArgs ca;
    ca.src[0] = query;  ca.dst[0] = qb;  ca.n8[0] = (int)(nAct / 8);
    ca.src[1] = key_in; ca.dst[1] = kb;  ca.n8[1] = (int)(nAct / 8);
    ca.src[2] = value;  ca.dst[2] = vb;  ca.n8[2] = (int)(nAct / 8);
    ca.src[3] = Wq;     ca.dst[3] = wqb; ca.n8[3] = (int)(nW / 8);
    ca.src[4] = Wk;     ca.dst[4] = wkb; ca.n8[4] = (int)(nW / 8);
    ca.src[5] = Wv;     ca.dst[5] = wvb; ca.n8[5] = (int)(nW / 8);
    ca.src[6] = Wo;     ca.dst[6] = wob; ca.n8[6] = (int)(nW / 8);
    cvt_multi<<<dim3(512, 7), 256, 0, stream>>>(ca);

    // 2. projections: 256x128 tiles -> QKV grid 768 = 3x256 CUs (perfect pack)
    if (fused_qkv) {
        QkvArgs qa;
        qa.A[0] = qb; qa.W[0] = wqb; qa.bias[0] = bq; qa.C[0] = qp;
        qa.A[1] = kb; qa.W[1] = wkb; qa.bias[1] = bk; qa.C[1] = kp;
        qa.A[2] = vb; qa.W[2] = wvb; qa.bias[2] = bv; qa.C[2] = vpT;
        dim3 g3(D_MODEL / 128, tokens / 256, 3);             // (16, 16, 3)
        gemm_qkv<<<g3, 512, 0, stream>>>(qa, tokens, D_MODEL, D_MODEL);
    } else {
        QkArgs qa;
        qa.A[0] = qb; qa.W[0] = wqb; qa.bias[0] = bq; qa.C[0] = qp;
        qa.A[1] = kb; qa.W[1] = wkb; qa.bias[1] = bk; qa.C[1] = kp;
        dim3 g2(D_MODEL / 128, tokens / 256, 2);             // (16, 16, 2)
        gemm_qk<<<g2, 512, 0, stream>>>(qa, tokens, D_MODEL, D_MODEL);
        dim3 gg(D_MODEL / 128, tokens / 256);
        gemm_bf16<bf16, true><<<gg, 512, 0, stream>>>(vb, wvb, bv, vpT, tokens, D_MODEL, D_MODEL);
    }

    // 3. attention
    dim3 ga(SEQ / 128, NUM_HEADS, BATCH);                    // (16, 16, 2)
    flash_attn_kernel<<<ga, 256, 0, stream>>>(qp, kp, vpT, ap);

    // 4. output projection (fp32 out): grid 256 = 1x256 CUs (perfect pack)
    dim3 gg(D_MODEL / 128, tokens / 256);
    gemm_bf16<float, false><<<gg, 512, 0, stream>>>(ap, wob, bo, out, tokens, D_MODEL, D_MODEL);
}

// Round 4
// 449.095 us; speedup vs baseline: 1.0880x; 1.0880x over previous
//
#include <hip/hip_runtime.h>
#include <hip/hip_bf16.h>
#include <stdint.h>

typedef __hip_bfloat16 bf16;
typedef __attribute__((ext_vector_type(8))) short bf16x8;   // 8 bf16 = 4 VGPRs (MFMA A/B frag)
typedef __attribute__((ext_vector_type(4))) float f32x4;    // MFMA C/D frag + 16B loads
typedef __attribute__((ext_vector_type(4))) short s16x4;    // 8B bf16 store

constexpr int D_MODEL   = 2048;
constexpr int NUM_HEADS = 16;
constexpr int HEAD_DIM  = 128;
constexpr int BATCH     = 2;
constexpr int SEQ       = 2048;

// GEMM tile geometry (shared by all GEMM kernels)
constexpr int GBM = 256, GBN = 128, GBK = 64;
constexpr int G_ABUF = GBM * GBK;            // 16384 elems (32 KB)
constexpr int G_BBUF = GBN * GBK;            // 8192  elems (16 KB)
constexpr int G_BUF  = G_ABUF + G_BBUF;      // 24576 elems (48 KB)
constexpr int G_LDS  = 3 * G_BUF;            // 73728 elems (144 KB)

// async global->LDS, 16B per lane; LDS dest must be wave-uniform base + lane*16
__device__ __forceinline__ void gload_lds16(const bf16* g, bf16* l) {
    __builtin_amdgcn_global_load_lds(
        (const __attribute__((address_space(1))) void*)g,
        (__attribute__((address_space(3))) void*)l, 16, 0, 0);
}

// ---------------------------------------------------------------------------
// fp32 -> bf16 bulk convert, up to 7 tensors in one launch (blockIdx.y selects)
// ---------------------------------------------------------------------------
struct CvtArgs { const float* src[7]; bf16* dst[7]; int n8[7]; };

__global__ __launch_bounds__(256)
void cvt_multi(CvtArgs a)
{
    const int t = blockIdx.y;
    const float* __restrict__ s = a.src[t];
    bf16* __restrict__ d = a.dst[t];
    const int n8 = a.n8[t];
    for (int i = blockIdx.x * 256 + threadIdx.x; i < n8; i += gridDim.x * 256) {
        f32x4 x = *(const f32x4*)(s + (size_t)i * 8);
        f32x4 y = *(const f32x4*)(s + (size_t)i * 8 + 4);
        bf16 t8[8] = { __float2bfloat16(x[0]), __float2bfloat16(x[1]),
                       __float2bfloat16(x[2]), __float2bfloat16(x[3]),
                       __float2bfloat16(y[0]), __float2bfloat16(y[1]),
                       __float2bfloat16(y[2]), __float2bfloat16(y[3]) };
        *(bf16x8*)(d + (size_t)i * 8) = *(const bf16x8*)t8;
    }
}

// ---------------------------------------------------------------------------
// GEMM core: C[M,N] = A[M,K] @ W[N,K]^T + bias
// BM=256 x BN=128, BK=64, 8 waves (4Mx2N, 64x64 per wave), 512 threads.
// kk-SPLIT SCHEDULE (round-4 change): 2 phases per K-tile, each phase =
// {stage 3 async loads; 8 ds_read_b128 (all frags of one k-half); barrier;
//  setprio(1); 16 independent MFMAs; setprio(0); barrier}. 4 barriers/K-tile
// (was 8 with triangle split whose 2/6/10/14-MFMA phases were bubble-bound:
//  measured 31% MfmaUtil, 3435 cyc/tile vs 1241 MFMA floor).
// Triple-buffered LDS (3 x 48KB = 144KB, 1 block/CU), counted vmcnt(6) only
// at tile boundaries (never 0 in steady state), XOR-swizzled LDS (round-3:
// verified bank-conflict = 0).
// NOTE: __shared__ lives in the __global__ wrapper (declared ONCE) — two
// instantiations in one kernel must SHARE it or static LDS doubles (r2 lesson).
// ---------------------------------------------------------------------------
template <typename TC, bool TRANS_PERM>
__device__ __forceinline__
void gemm_body(const bf16* __restrict__ A, const bf16* __restrict__ W,
               const float* __restrict__ bias, TC* __restrict__ C,
               int M, int N, int K, bf16* smem)
{
    const int tid  = threadIdx.x;
    const int lane = tid & 63;
    const int wave = tid >> 6;               // 0..7
    const int quad = lane >> 4, l16 = lane & 15;
    const int sw   = l16 & 7;
    const int wr   = wave >> 1;              // 0..3 : M direction, 64 rows
    const int wc   = wave & 1;               // 0..1 : N direction, 64 cols
    const int m0   = blockIdx.y * GBM, n0 = blockIdx.x * GBN;

    // staging thread-invariants: chunk c = u*512 + tid; row = u*64 + (tid>>3),
    // slot = tid&7, fetched global chunk g = slot ^ (row&7)  (involution)
    const int rloc = tid >> 3;               // 0..63
    const int gsw  = (tid & 7) ^ (rloc & 7);
    const int NT   = K / GBK;

    const bf16* Abase = A + (size_t)(m0 + rloc) * K + gsw * 8;
    const bf16* Bbase = W + (size_t)(n0 + rloc) * K + gsw * 8;
    const size_t rstep = (size_t)64 * K;

    auto stageA = [&](int t, int bi, int u) {
        gload_lds16(Abase + u * rstep + (size_t)t * GBK,
                    smem + bi * G_BUF + (u * 512 + tid) * 8);
    };
    auto stageB = [&](int t, int bi, int u) {
        gload_lds16(Bbase + u * rstep + (size_t)t * GBK,
                    smem + bi * G_BUF + G_ABUF + (u * 512 + tid) * 8);
    };

    f32x4 acc[4][4];
#pragma unroll
    for (int i = 0; i < 4; i++)
#pragma unroll
        for (int j = 0; j < 4; j++) acc[i][j] = (f32x4){0.f, 0.f, 0.f, 0.f};

    // prologue: stage tiles 0 and 1 (12 loads/thread in flight)
#pragma unroll
    for (int u = 0; u < 4; u++) stageA(0, 0, u);
#pragma unroll
    for (int u = 0; u < 2; u++) stageB(0, 0, u);
    if (NT > 1) {
#pragma unroll
        for (int u = 0; u < 4; u++) stageA(1, 1, u);
#pragma unroll
        for (int u = 0; u < 2; u++) stageB(1, 1, u);
        asm volatile("s_waitcnt vmcnt(6)" ::: "memory");   // tile 0 landed
    } else {
        asm volatile("s_waitcnt vmcnt(0)" ::: "memory");
    }
    asm volatile("s_barrier" ::: "memory");

    int bc = 0;                              // buffer holding tile t
    for (int t = 0; t < NT; ++t) {
        const bf16* sAc = smem + bc * G_BUF;
        const bf16* sBc = sAc + G_ABUF;
        const int bs = (bc + 2 >= 3) ? bc - 1 : bc + 2;   // buffer for tile t+2
        const bool pf = (t + 2 < NT);

        // ---- phase 0 : k-half 0 (chunks quad^sw), 16 MFMAs ----
        if (pf) { stageA(t + 2, bs, 0); stageA(t + 2, bs, 1); stageA(t + 2, bs, 2); }
        bf16x8 a0[4], b0[4];
#pragma unroll
        for (int i = 0; i < 4; i++)
            a0[i] = *(const bf16x8*)&sAc[(wr * 64 + i * 16 + l16) * 64 + (quad ^ sw) * 8];
#pragma unroll
        for (int j = 0; j < 4; j++)
            b0[j] = *(const bf16x8*)&sBc[(wc * 64 + j * 16 + l16) * 64 + (quad ^ sw) * 8];
        __builtin_amdgcn_s_barrier();
        __builtin_amdgcn_s_setprio(1);
#pragma unroll
        for (int i = 0; i < 4; i++)
#pragma unroll
            for (int j = 0; j < 4; j++)
                acc[i][j] = __builtin_amdgcn_mfma_f32_16x16x32_bf16(a0[i], b0[j], acc[i][j], 0, 0, 0);
        __builtin_amdgcn_s_setprio(0);
        __builtin_amdgcn_s_barrier();

        // ---- phase 1 : k-half 1 (chunks (4+quad)^sw), 16 MFMAs ----
        if (pf) { stageA(t + 2, bs, 3); stageB(t + 2, bs, 0); stageB(t + 2, bs, 1); }
        bf16x8 a1[4], b1[4];
#pragma unroll
        for (int i = 0; i < 4; i++)
            a1[i] = *(const bf16x8*)&sAc[(wr * 64 + i * 16 + l16) * 64 + ((4 + quad) ^ sw) * 8];
#pragma unroll
        for (int j = 0; j < 4; j++)
            b1[j] = *(const bf16x8*)&sBc[(wc * 64 + j * 16 + l16) * 64 + ((4 + quad) ^ sw) * 8];
        __builtin_amdgcn_s_barrier();
        __builtin_amdgcn_s_setprio(1);
#pragma unroll
        for (int i = 0; i < 4; i++)
#pragma unroll
            for (int j = 0; j < 4; j++)
                acc[i][j] = __builtin_amdgcn_mfma_f32_16x16x32_bf16(a1[i], b1[j], acc[i][j], 0, 0, 0);
        __builtin_amdgcn_s_setprio(0);

        // tile boundary: own-wave counted wait, then collective barrier.
        // vmcnt(6) leaves exactly tile t+2's 6 loads in flight => tile t+1's
        // LDS writes have landed for every wave after the barrier.
        if (pf)                asm volatile("s_waitcnt vmcnt(6)" ::: "memory");
        else if (t + 1 < NT)   asm volatile("s_waitcnt vmcnt(0)" ::: "memory");
        asm volatile("s_barrier" ::: "memory");
        bc = (bc + 1 == 3) ? 0 : bc + 1;
    }

    // epilogue: C/D layout col=lane&15 (B-frag row), row=quad*4+reg (A-frag row)
#pragma unroll
    for (int j = 0; j < 4; j++) {
        const int col = n0 + wc * 64 + j * 16 + l16;
        const float bv = bias[col];
#pragma unroll
        for (int i = 0; i < 4; i++) {
            const int row0 = m0 + wr * 64 + i * 16 + quad * 4;
            if constexpr (TRANS_PERM) {
                // V output: [b][h][dh][s'] with the flash key-permutation applied
                // within each 64-token group: pos p = c*32 + qh*8 + t*4 + r holds
                // key (2c+t)*16 + qh*4 + r.
                int g   = row0 & 63;                           // g & 3 == 0
                int tau = g >> 4, qh = (g >> 2) & 3;
                int pp  = (tau >> 1) * 32 + qh * 8 + (tau & 1) * 4;
                int sp  = ((row0 & 2047) & ~63) | pp;
                size_t idx = (size_t)(row0 >> 11) * ((size_t)D_MODEL * SEQ)
                           + (size_t)col * SEQ + sp;
                bf16 t4[4];
#pragma unroll
                for (int r = 0; r < 4; r++) t4[r] = __float2bfloat16(acc[i][j][r] + bv);
                *(s16x4*)&C[idx] = *(const s16x4*)t4;
            } else {
#pragma unroll
                for (int r = 0; r < 4; r++) {
                    int row = row0 + r;
                    if constexpr (sizeof(TC) == 2)
                        C[(size_t)row * N + col] = (TC)__float2bfloat16(acc[i][j][r] + bv);
                    else
                        C[(size_t)row * N + col] = (TC)(acc[i][j][r] + bv);
                }
            }
        }
    }
}

template <typename TC, bool TRANS_PERM>
__global__ __launch_bounds__(512, 1)
void gemm_bf16(const bf16* __restrict__ A, const bf16* __restrict__ W,
               const float* __restrict__ bias, TC* __restrict__ C,
               int M, int N, int K)
{
    __shared__ bf16 smem[G_LDS];
    gemm_body<TC, TRANS_PERM>(A, W, bias, C, M, N, K, smem);
}

// fused Q+K+V projections: blockIdx.z selects tensor; z==2 is V (trans+perm)
struct QkvArgs { const bf16* A[3]; const bf16* W[3]; const float* bias[3]; bf16* C[3]; };

__global__ __launch_bounds__(512, 1)
void gemm_qkv(QkvArgs ga, int M, int N, int K)
{
    __shared__ bf16 smem[G_LDS];             // ONE buffer, shared by both paths
    const int z = blockIdx.z;
    if (z == 2) gemm_body<bf16, true >(ga.A[2], ga.W[2], ga.bias[2], ga.C[2], M, N, K, smem);
    else        gemm_body<bf16, false>(ga.A[z], ga.W[z], ga.bias[z], ga.C[z], M, N, K, smem);
}

// fused Q+K only (fallback when ws is tight)
struct QkArgs { const bf16* A[2]; const bf16* W[2]; const float* bias[2]; bf16* C[2]; };

__global__ __launch_bounds__(512, 1)
void gemm_qk(QkArgs ga, int M, int N, int K)
{
    __shared__ bf16 smem[G_LDS];
    const int z = blockIdx.z;
    gemm_body<bf16, false>(ga.A[z], ga.W[z], ga.bias[z], ga.C[z], M, N, K, smem);
}

// ---------------------------------------------------------------------------
// Flash attention v3: operand-swapped (S^T/O^T), no-max softmax, P in regs,
// double-buffered async K/V staging (global_load_lds 16B, XOR-swizzled LDS),
// ONE barrier per K-tile iteration.  (unchanged this round)
// ---------------------------------------------------------------------------
__global__ __launch_bounds__(256)
void flash_attn_kernel(const bf16* __restrict__ Qp, const bf16* __restrict__ Kp,
                       const bf16* __restrict__ Vt, bf16* __restrict__ Op)
{
    constexpr int BQ = 128, BKV = 64, DH = 128;
    __shared__ bf16 sK[2][BKV * DH];       // 2 x 16 KB
    __shared__ bf16 sV[2][DH * BKV];       // 2 x 16 KB

    const int tid  = threadIdx.x;
    const int wave = tid >> 6, lane = tid & 63;
    const int quad = lane >> 4, l16 = lane & 15;
    const int q0 = blockIdx.x * BQ;
    const int h  = blockIdx.y;
    const int b  = blockIdx.z;

    const size_t base  = (size_t)b * SEQ * D_MODEL + (size_t)h * HEAD_DIM;
    const size_t basev = ((size_t)b * NUM_HEADS + h) * (size_t)HEAD_DIM * SEQ;
    const bf16* Kb = Kp + base;
    const bf16* Vb = Vt + basev;

    auto stage = [&](int t, int bi) {
        const bf16* Kt = Kb + (size_t)t * BKV * D_MODEL;
        const bf16* Vtile = Vb + (size_t)t * BKV;
        bf16* sKb = sK[bi];
        bf16* sVb = sV[bi];
#pragma unroll
        for (int s = 0; s < 4; s++) {
            int c = s * 256 + wave * 64 + lane;            // 0..1023
            int row = c >> 4, gs = c & 15;
            int g = gs ^ (row & 15);
            gload_lds16(Kt + (size_t)row * D_MODEL + g * 8, sKb + (size_t)c * 8);
        }
#pragma unroll
        for (int s = 0; s < 4; s++) {
            int c = s * 256 + wave * 64 + lane;            // 0..1023
            int dh = c >> 3, gs = c & 7;
            int g = gs ^ (dh & 7);
            gload_lds16(Vtile + (size_t)dh * SEQ + g * 8, sVb + (size_t)c * 8);
        }
    };

    bf16x8 bq[2][4];
#pragma unroll
    for (int nt = 0; nt < 2; nt++)
#pragma unroll
        for (int kk = 0; kk < 4; kk++)
            bq[nt][kk] = *(const bf16x8*)&Qp[base +
                (size_t)(q0 + wave * 32 + nt * 16 + l16) * D_MODEL + kk * 32 + quad * 8];

    f32x4 oacc[2][8];
#pragma unroll
    for (int nt = 0; nt < 2; nt++)
#pragma unroll
        for (int mt = 0; mt < 8; mt++) oacc[nt][mt] = (f32x4){0.f, 0.f, 0.f, 0.f};

    float lsum[2] = {0.f, 0.f};

    const float SCL2E = 0.08838834764831845f * 1.4426950408889634f;
    constexpr int NT = SEQ / BKV;          // 32

    stage(0, 0);

    for (int t = 0; t < NT; ++t) {
        __syncthreads();
        if (t + 1 < NT) stage(t + 1, (t + 1) & 1);

        const bf16* sKc = sK[t & 1];
        const bf16* sVc = sV[t & 1];

        f32x4 sacc[2][4];
#pragma unroll
        for (int nt = 0; nt < 2; nt++)
#pragma unroll
            for (int kt = 0; kt < 4; kt++) sacc[nt][kt] = (f32x4){0.f, 0.f, 0.f, 0.f};
#pragma unroll
        for (int kk = 0; kk < 4; kk++) {
            bf16x8 ak[4];
#pragma unroll
            for (int kt = 0; kt < 4; kt++) {
                int row = kt * 16 + l16;
                int g   = (kk * 4 + quad) ^ l16;
                ak[kt] = *(const bf16x8*)&sKc[(size_t)row * DH + g * 8];
            }
#pragma unroll
            for (int nt = 0; nt < 2; nt++)
#pragma unroll
                for (int kt = 0; kt < 4; kt++)
                    sacc[nt][kt] = __builtin_amdgcn_mfma_f32_16x16x32_bf16(ak[kt], bq[nt][kk], sacc[nt][kt], 0, 0, 0);
        }

        bf16x8 pb[2][2];
#pragma unroll
        for (int nt = 0; nt < 2; nt++) {
            bf16 tmp[16];
#pragma unroll
            for (int kt = 0; kt < 4; kt++) {
#pragma unroll
                for (int r = 0; r < 4; r++) {
                    float p = exp2f(fminf(sacc[nt][kt][r] * SCL2E, 60.f));
                    lsum[nt] += p;
                    tmp[(kt >> 1) * 8 + (kt & 1) * 4 + r] = __float2bfloat16(p);
                }
            }
            pb[nt][0] = *(const bf16x8*)&tmp[0];
            pb[nt][1] = *(const bf16x8*)&tmp[8];
        }

#pragma unroll
        for (int c = 0; c < 2; c++) {
#pragma unroll
            for (int mt = 0; mt < 8; mt++) {
                int row = mt * 16 + l16;
                int g   = (c * 4 + quad) ^ (l16 & 7);
                bf16x8 av = *(const bf16x8*)&sVc[(size_t)row * BKV + g * 8];
#pragma unroll
                for (int nt = 0; nt < 2; nt++)
                    oacc[nt][mt] = __builtin_amdgcn_mfma_f32_16x16x32_bf16(av, pb[nt][c], oacc[nt][mt], 0, 0, 0);
            }
        }
    }

#pragma unroll
    for (int nt = 0; nt < 2; nt++) {
        float v = lsum[nt];
        v += __shfl_xor(v, 16);
        v += __shfl_xor(v, 32);
        lsum[nt] = v;
    }

#pragma unroll
    for (int nt = 0; nt < 2; nt++) {
        float inv = 1.f / lsum[nt];
        int row = q0 + wave * 32 + nt * 16 + l16;
#pragma unroll
        for (int mt = 0; mt < 8; mt++) {
            bf16 t4[4];
#pragma unroll
            for (int r = 0; r < 4; r++) t4[r] = __float2bfloat16(oacc[nt][mt][r] * inv);
            *(s16x4*)&Op[base + (size_t)row * D_MODEL + mt * 16 + quad * 4] = *(const s16x4*)t4;
        }
    }
}

// ---------------------------------------------------------------------------
extern "C" void kernel_launch(void* const* d_in, const int* in_sizes, int n_in,
                              void* d_out, int out_size, void* d_ws, size_t ws_size,
                              hipStream_t stream)
{
    const float* query  = (const float*)d_in[0];
    const float* key_in = (const float*)d_in[1];
    const float* value  = (const float*)d_in[2];
    const float* Wq = (const float*)d_in[3];
    const float* bq = (const float*)d_in[4];
    const float* Wk = (const float*)d_in[5];
    const float* bk = (const float*)d_in[6];
    const float* Wv = (const float*)d_in[7];
    const float* bv = (const float*)d_in[8];
    const float* Wo = (const float*)d_in[9];
    const float* bo = (const float*)d_in[10];
    float* out = (float*)d_out;

    const int tokens = BATCH * SEQ;                          // 4096
    const size_t nAct = (size_t)tokens * D_MODEL;            // 8.4M elems
    const size_t nW   = (size_t)D_MODEL * D_MODEL;           // 4.2M elems

    const bool fused_qkv = ws_size >= (6 * nAct + 4 * nW) * sizeof(bf16);

    bf16* p = (bf16*)d_ws;
    bf16* qb  = p; p += nAct;      // bf16 activations
    bf16* kb  = p; p += nAct;
    bf16* vb  = p; p += nAct;
    bf16* wqb = p; p += nW;        // bf16 weights
    bf16* wkb = p; p += nW;
    bf16* wvb = p; p += nW;
    bf16* wob = p; p += nW;
    bf16* qp  = p; p += nAct;      // Q,K projections
    bf16* kp  = p; p += nAct;
    bf16* vpT;                     // V projection (transposed+permuted)
    if (fused_qkv) { vpT = p; p += nAct; }
    else           { vpT = qb; }   // fallback: alias (QK launch consumes qb first)
    bf16* ap = fused_qkv ? qb : kb; // attn out: aliases an activation consumed earlier

    // 1. fp32 -> bf16 (one launch)
    CvtArgs ca;
    ca.src[0] = query;  ca.dst[0] = qb;  ca.n8[0] = (int)(nAct / 8);
    ca.src[1] = key_in; ca.dst[1] = kb;  ca.n8[1] = (int)(nAct / 8);
    ca.src[2] = value;  ca.dst[2] = vb;  ca.n8[2] = (int)(nAct / 8);
    ca.src[3] = Wq;     ca.dst[3] = wqb; ca.n8[3] = (int)(nW / 8);
    ca.src[4] = Wk;     ca.dst[4] = wkb; ca.n8[4] = (int)(nW / 8);
    ca.src[5] = Wv;     ca.dst[5] = wvb; ca.n8[5] = (int)(nW / 8);
    ca.src[6] = Wo;     ca.dst[6] = wob; ca.n8[6] = (int)(nW / 8);
    cvt_multi<<<dim3(512, 7), 256, 0, stream>>>(ca);

    // 2. projections: 256x128 tiles -> QKV grid 768 = 3x256 CUs (perfect pack)
    if (fused_qkv) {
        QkvArgs qa;
        qa.A[0] = qb; qa.W[0] = wqb; qa.bias[0] = bq; qa.C[0] = qp;
        qa.A[1] = kb; qa.W[1] = wkb; qa.bias[1] = bk; qa.C[1] = kp;
        qa.A[2] = vb; qa.W[2] = wvb; qa.bias[2] = bv; qa.C[2] = vpT;
        dim3 g3(D_MODEL / 128, tokens / 256, 3);             // (16, 16, 3)
        gemm_qkv<<<g3, 512, 0, stream>>>(qa, tokens, D_MODEL, D_MODEL);
    } else {
        QkArgs qa;
        qa.A[0] = qb; qa.W[0] = wqb; qa.bias[0] = bq; qa.C[0] = qp;
        qa.A[1] = kb; qa.W[1] = wkb; qa.bias[1] = bk; qa.C[1] = kp;
        dim3 g2(D_MODEL / 128, tokens / 256, 2);             // (16, 16, 2)
        gemm_qk<<<g2, 512, 0, stream>>>(qa, tokens, D_MODEL, D_MODEL);
        dim3 gg(D_MODEL / 128, tokens / 256);
        gemm_bf16<bf16, true><<<gg, 512, 0, stream>>>(vb, wvb, bv, vpT, tokens, D_MODEL, D_MODEL);
    }

    // 3. attention
    dim3 ga(SEQ / 128, NUM_HEADS, BATCH);                    // (16, 16, 2)
    flash_attn_kernel<<<ga, 256, 0, stream>>>(qp, kp, vpT, ap);

    // 4. output projection (fp32 out): grid 256 = 1x256 CUs (perfect pack)
    dim3 gg(D_MODEL / 128, tokens / 256);
    gemm_bf16<float, false><<<gg, 512, 0, stream>>>(ap, wob, bo, out, tokens, D_MODEL, D_MODEL);
}

// Round 5
// 442.239 us; speedup vs baseline: 1.1049x; 1.0155x over previous
//
#include <hip/hip_runtime.h>
#include <hip/hip_bf16.h>
#include <stdint.h>

typedef __hip_bfloat16 bf16;
typedef __attribute__((ext_vector_type(8))) short bf16x8;   // 8 bf16 = 4 VGPRs (MFMA A/B frag)
typedef __attribute__((ext_vector_type(4))) float f32x4;    // MFMA C/D frag + 16B loads
typedef __attribute__((ext_vector_type(4))) short s16x4;    // 8B bf16 store

constexpr int D_MODEL   = 2048;
constexpr int NUM_HEADS = 16;
constexpr int HEAD_DIM  = 128;
constexpr int BATCH     = 2;
constexpr int SEQ       = 2048;

// GEMM tile geometry (shared by all GEMM kernels)
constexpr int GBM = 256, GBN = 128, GBK = 64;
constexpr int G_ABUF = GBM * GBK;            // 16384 elems (32 KB)
constexpr int G_BBUF = GBN * GBK;            // 8192  elems (16 KB)
constexpr int G_BUF  = G_ABUF + G_BBUF;      // 24576 elems (48 KB)
constexpr int G_LDS  = 3 * G_BUF;            // 73728 elems (144 KB)

// async global->LDS, 16B per lane; LDS dest must be wave-uniform base + lane*16
__device__ __forceinline__ void gload_lds16(const bf16* g, bf16* l) {
    __builtin_amdgcn_global_load_lds(
        (const __attribute__((address_space(1))) void*)g,
        (__attribute__((address_space(3))) void*)l, 16, 0, 0);
}

// ---------------------------------------------------------------------------
// fp32 -> bf16 bulk convert, up to 7 tensors in one launch (blockIdx.y selects)
// ---------------------------------------------------------------------------
struct CvtArgs { const float* src[7]; bf16* dst[7]; int n8[7]; };

__global__ __launch_bounds__(256)
void cvt_multi(CvtArgs a)
{
    const int t = blockIdx.y;
    const float* __restrict__ s = a.src[t];
    bf16* __restrict__ d = a.dst[t];
    const int n8 = a.n8[t];
    for (int i = blockIdx.x * 256 + threadIdx.x; i < n8; i += gridDim.x * 256) {
        f32x4 x = *(const f32x4*)(s + (size_t)i * 8);
        f32x4 y = *(const f32x4*)(s + (size_t)i * 8 + 4);
        bf16 t8[8] = { __float2bfloat16(x[0]), __float2bfloat16(x[1]),
                       __float2bfloat16(x[2]), __float2bfloat16(x[3]),
                       __float2bfloat16(y[0]), __float2bfloat16(y[1]),
                       __float2bfloat16(y[2]), __float2bfloat16(y[3]) };
        *(bf16x8*)(d + (size_t)i * 8) = *(const bf16x8*)t8;
    }
}

// ---------------------------------------------------------------------------
// GEMM core: C[M,N] = A[M,K] @ W[N,K]^T + bias
// BM=256 x BN=128, BK=64, 8 waves (4Mx2N, 64x64 per wave), 512 threads.
// ROUND-5 SCHEDULE: intra-tile barriers REMOVED (phases 0/1 read the SAME
// buffer — the barriers were pure lockstep: r4 measured LDS service (1540cy)
// + MFMA (1241cy) taking strict turns, 3175 cyc/tile, MfmaUtil 35%).
// Now: per tile {issue 6 stage loads; issue ALL 16 ds_read_b128; 32 MFMAs
// half0->half1}. Compiler emits counted lgkmcnt, so the half-1 reads are
// served by the LDS pipe UNDER the half-0 MFMAs; 2 waves/SIMD drift freely
// (setprio favors the MFMA wave). ONE barrier + counted vmcnt(6) per tile
// (boundary only — buffer-rotation proof unchanged from r3/r4).
// Triple-buffered LDS (3 x 48KB = 144KB, 1 block/CU), XOR-swizzled
// (r3-verified: SQ_LDS_BANK_CONFLICT = 0).
// NOTE: __shared__ lives in the __global__ wrapper (declared ONCE) — two
// instantiations in one kernel must SHARE it or static LDS doubles (r2 lesson).
// ---------------------------------------------------------------------------
template <typename TC, bool TRANS_PERM>
__device__ __forceinline__
void gemm_body(const bf16* __restrict__ A, const bf16* __restrict__ W,
               const float* __restrict__ bias, TC* __restrict__ C,
               int M, int N, int K, bf16* smem)
{
    const int tid  = threadIdx.x;
    const int lane = tid & 63;
    const int wave = tid >> 6;               // 0..7
    const int quad = lane >> 4, l16 = lane & 15;
    const int sw   = l16 & 7;
    const int wr   = wave >> 1;              // 0..3 : M direction, 64 rows
    const int wc   = wave & 1;               // 0..1 : N direction, 64 cols
    const int m0   = blockIdx.y * GBM, n0 = blockIdx.x * GBN;

    // staging thread-invariants: chunk c = u*512 + tid; row = u*64 + (tid>>3),
    // slot = tid&7, fetched global chunk g = slot ^ (row&7)  (involution)
    const int rloc = tid >> 3;               // 0..63
    const int gsw  = (tid & 7) ^ (rloc & 7);
    const int NT   = K / GBK;

    const bf16* Abase = A + (size_t)(m0 + rloc) * K + gsw * 8;
    const bf16* Bbase = W + (size_t)(n0 + rloc) * K + gsw * 8;
    const size_t rstep = (size_t)64 * K;

    auto stageA = [&](int t, int bi, int u) {
        gload_lds16(Abase + u * rstep + (size_t)t * GBK,
                    smem + bi * G_BUF + (u * 512 + tid) * 8);
    };
    auto stageB = [&](int t, int bi, int u) {
        gload_lds16(Bbase + u * rstep + (size_t)t * GBK,
                    smem + bi * G_BUF + G_ABUF + (u * 512 + tid) * 8);
    };

    f32x4 acc[4][4];
#pragma unroll
    for (int i = 0; i < 4; i++)
#pragma unroll
        for (int j = 0; j < 4; j++) acc[i][j] = (f32x4){0.f, 0.f, 0.f, 0.f};

    // prologue: stage tiles 0 and 1 (12 loads/thread in flight)
#pragma unroll
    for (int u = 0; u < 4; u++) stageA(0, 0, u);
#pragma unroll
    for (int u = 0; u < 2; u++) stageB(0, 0, u);
    if (NT > 1) {
#pragma unroll
        for (int u = 0; u < 4; u++) stageA(1, 1, u);
#pragma unroll
        for (int u = 0; u < 2; u++) stageB(1, 1, u);
        asm volatile("s_waitcnt vmcnt(6)" ::: "memory");   // tile 0 landed
    } else {
        asm volatile("s_waitcnt vmcnt(0)" ::: "memory");
    }
    asm volatile("s_barrier" ::: "memory");

    int bc = 0;                              // buffer holding tile t
    for (int t = 0; t < NT; ++t) {
        const bf16* sAc = smem + bc * G_BUF;
        const bf16* sBc = sAc + G_ABUF;
        const int bs = (bc + 2 >= 3) ? bc - 1 : bc + 2;   // buffer for tile t+2
        const bool pf = (t + 2 < NT);

        // issue tile-(t+2) staging first: HBM latency spans two full tiles
        if (pf) {
            stageA(t + 2, bs, 0); stageA(t + 2, bs, 1);
            stageA(t + 2, bs, 2); stageA(t + 2, bs, 3);
            stageB(t + 2, bs, 0); stageB(t + 2, bs, 1);
        }

        // issue ALL 16 ds_read_b128 for this tile (both k-halves); the
        // compiler's counted lgkmcnt lets half-1 service run under half-0 MFMAs
        bf16x8 a0[4], b0[4], a1[4], b1[4];
#pragma unroll
        for (int i = 0; i < 4; i++)
            a0[i] = *(const bf16x8*)&sAc[(wr * 64 + i * 16 + l16) * 64 + (quad ^ sw) * 8];
#pragma unroll
        for (int j = 0; j < 4; j++)
            b0[j] = *(const bf16x8*)&sBc[(wc * 64 + j * 16 + l16) * 64 + (quad ^ sw) * 8];
#pragma unroll
        for (int i = 0; i < 4; i++)
            a1[i] = *(const bf16x8*)&sAc[(wr * 64 + i * 16 + l16) * 64 + ((4 + quad) ^ sw) * 8];
#pragma unroll
        for (int j = 0; j < 4; j++)
            b1[j] = *(const bf16x8*)&sBc[(wc * 64 + j * 16 + l16) * 64 + ((4 + quad) ^ sw) * 8];

        __builtin_amdgcn_s_setprio(1);
#pragma unroll
        for (int i = 0; i < 4; i++)
#pragma unroll
            for (int j = 0; j < 4; j++)
                acc[i][j] = __builtin_amdgcn_mfma_f32_16x16x32_bf16(a0[i], b0[j], acc[i][j], 0, 0, 0);
#pragma unroll
        for (int i = 0; i < 4; i++)
#pragma unroll
            for (int j = 0; j < 4; j++)
                acc[i][j] = __builtin_amdgcn_mfma_f32_16x16x32_bf16(a1[i], b1[j], acc[i][j], 0, 0, 0);
        __builtin_amdgcn_s_setprio(0);

        // tile boundary: own-wave counted wait, then collective barrier.
        // vmcnt(6) leaves exactly tile t+2's 6 loads in flight => tile t+1's
        // LDS writes have landed for every wave after the barrier.
        if (pf)                asm volatile("s_waitcnt vmcnt(6)" ::: "memory");
        else if (t + 1 < NT)   asm volatile("s_waitcnt vmcnt(0)" ::: "memory");
        asm volatile("s_barrier" ::: "memory");
        bc = (bc + 1 == 3) ? 0 : bc + 1;
    }

    // epilogue: C/D layout col=lane&15 (B-frag row), row=quad*4+reg (A-frag row)
#pragma unroll
    for (int j = 0; j < 4; j++) {
        const int col = n0 + wc * 64 + j * 16 + l16;
        const float bv = bias[col];
#pragma unroll
        for (int i = 0; i < 4; i++) {
            const int row0 = m0 + wr * 64 + i * 16 + quad * 4;
            if constexpr (TRANS_PERM) {
                // V output: [b][h][dh][s'] with the flash key-permutation applied
                // within each 64-token group: pos p = c*32 + qh*8 + t*4 + r holds
                // key (2c+t)*16 + qh*4 + r.
                int g   = row0 & 63;                           // g & 3 == 0
                int tau = g >> 4, qh = (g >> 2) & 3;
                int pp  = (tau >> 1) * 32 + qh * 8 + (tau & 1) * 4;
                int sp  = ((row0 & 2047) & ~63) | pp;
                size_t idx = (size_t)(row0 >> 11) * ((size_t)D_MODEL * SEQ)
                           + (size_t)col * SEQ + sp;
                bf16 t4[4];
#pragma unroll
                for (int r = 0; r < 4; r++) t4[r] = __float2bfloat16(acc[i][j][r] + bv);
                *(s16x4*)&C[idx] = *(const s16x4*)t4;
            } else {
#pragma unroll
                for (int r = 0; r < 4; r++) {
                    int row = row0 + r;
                    if constexpr (sizeof(TC) == 2)
                        C[(size_t)row * N + col] = (TC)__float2bfloat16(acc[i][j][r] + bv);
                    else
                        C[(size_t)row * N + col] = (TC)(acc[i][j][r] + bv);
                }
            }
        }
    }
}

template <typename TC, bool TRANS_PERM>
__global__ __launch_bounds__(512, 1)
void gemm_bf16(const bf16* __restrict__ A, const bf16* __restrict__ W,
               const float* __restrict__ bias, TC* __restrict__ C,
               int M, int N, int K)
{
    __shared__ bf16 smem[G_LDS];
    gemm_body<TC, TRANS_PERM>(A, W, bias, C, M, N, K, smem);
}

// fused Q+K+V projections: blockIdx.z selects tensor; z==2 is V (trans+perm)
struct QkvArgs { const bf16* A[3]; const bf16* W[3]; const float* bias[3]; bf16* C[3]; };

__global__ __launch_bounds__(512, 1)
void gemm_qkv(QkvArgs ga, int M, int N, int K)
{
    __shared__ bf16 smem[G_LDS];             // ONE buffer, shared by both paths
    const int z = blockIdx.z;
    if (z == 2) gemm_body<bf16, true >(ga.A[2], ga.W[2], ga.bias[2], ga.C[2], M, N, K, smem);
    else        gemm_body<bf16, false>(ga.A[z], ga.W[z], ga.bias[z], ga.C[z], M, N, K, smem);
}

// fused Q+K only (fallback when ws is tight)
struct QkArgs { const bf16* A[2]; const bf16* W[2]; const float* bias[2]; bf16* C[2]; };

__global__ __launch_bounds__(512, 1)
void gemm_qk(QkArgs ga, int M, int N, int K)
{
    __shared__ bf16 smem[G_LDS];
    const int z = blockIdx.z;
    gemm_body<bf16, false>(ga.A[z], ga.W[z], ga.bias[z], ga.C[z], M, N, K, smem);
}

// ---------------------------------------------------------------------------
// Flash attention v3: operand-swapped (S^T/O^T), no-max softmax, P in regs,
// double-buffered async K/V staging (global_load_lds 16B, XOR-swizzled LDS),
// ONE barrier per K-tile iteration.  (unchanged this round)
// ---------------------------------------------------------------------------
__global__ __launch_bounds__(256)
void flash_attn_kernel(const bf16* __restrict__ Qp, const bf16* __restrict__ Kp,
                       const bf16* __restrict__ Vt, bf16* __restrict__ Op)
{
    constexpr int BQ = 128, BKV = 64, DH = 128;
    __shared__ bf16 sK[2][BKV * DH];       // 2 x 16 KB
    __shared__ bf16 sV[2][DH * BKV];       // 2 x 16 KB

    const int tid  = threadIdx.x;
    const int wave = tid >> 6, lane = tid & 63;
    const int quad = lane >> 4, l16 = lane & 15;
    const int q0 = blockIdx.x * BQ;
    const int h  = blockIdx.y;
    const int b  = blockIdx.z;

    const size_t base  = (size_t)b * SEQ * D_MODEL + (size_t)h * HEAD_DIM;
    const size_t basev = ((size_t)b * NUM_HEADS + h) * (size_t)HEAD_DIM * SEQ;
    const bf16* Kb = Kp + base;
    const bf16* Vb = Vt + basev;

    auto stage = [&](int t, int bi) {
        const bf16* Kt = Kb + (size_t)t * BKV * D_MODEL;
        const bf16* Vtile = Vb + (size_t)t * BKV;
        bf16* sKb = sK[bi];
        bf16* sVb = sV[bi];
#pragma unroll
        for (int s = 0; s < 4; s++) {
            int c = s * 256 + wave * 64 + lane;            // 0..1023
            int row = c >> 4, gs = c & 15;
            int g = gs ^ (row & 15);
            gload_lds16(Kt + (size_t)row * D_MODEL + g * 8, sKb + (size_t)c * 8);
        }
#pragma unroll
        for (int s = 0; s < 4; s++) {
            int c = s * 256 + wave * 64 + lane;            // 0..1023
            int dh = c >> 3, gs = c & 7;
            int g = gs ^ (dh & 7);
            gload_lds16(Vtile + (size_t)dh * SEQ + g * 8, sVb + (size_t)c * 8);
        }
    };

    bf16x8 bq[2][4];
#pragma unroll
    for (int nt = 0; nt < 2; nt++)
#pragma unroll
        for (int kk = 0; kk < 4; kk++)
            bq[nt][kk] = *(const bf16x8*)&Qp[base +
                (size_t)(q0 + wave * 32 + nt * 16 + l16) * D_MODEL + kk * 32 + quad * 8];

    f32x4 oacc[2][8];
#pragma unroll
    for (int nt = 0; nt < 2; nt++)
#pragma unroll
        for (int mt = 0; mt < 8; mt++) oacc[nt][mt] = (f32x4){0.f, 0.f, 0.f, 0.f};

    float lsum[2] = {0.f, 0.f};

    const float SCL2E = 0.08838834764831845f * 1.4426950408889634f;
    constexpr int NT = SEQ / BKV;          // 32

    stage(0, 0);

    for (int t = 0; t < NT; ++t) {
        __syncthreads();
        if (t + 1 < NT) stage(t + 1, (t + 1) & 1);

        const bf16* sKc = sK[t & 1];
        const bf16* sVc = sV[t & 1];

        f32x4 sacc[2][4];
#pragma unroll
        for (int nt = 0; nt < 2; nt++)
#pragma unroll
            for (int kt = 0; kt < 4; kt++) sacc[nt][kt] = (f32x4){0.f, 0.f, 0.f, 0.f};
#pragma unroll
        for (int kk = 0; kk < 4; kk++) {
            bf16x8 ak[4];
#pragma unroll
            for (int kt = 0; kt < 4; kt++) {
                int row = kt * 16 + l16;
                int g   = (kk * 4 + quad) ^ l16;
                ak[kt] = *(const bf16x8*)&sKc[(size_t)row * DH + g * 8];
            }
#pragma unroll
            for (int nt = 0; nt < 2; nt++)
#pragma unroll
                for (int kt = 0; kt < 4; kt++)
                    sacc[nt][kt] = __builtin_amdgcn_mfma_f32_16x16x32_bf16(ak[kt], bq[nt][kk], sacc[nt][kt], 0, 0, 0);
        }

        bf16x8 pb[2][2];
#pragma unroll
        for (int nt = 0; nt < 2; nt++) {
            bf16 tmp[16];
#pragma unroll
            for (int kt = 0; kt < 4; kt++) {
#pragma unroll
                for (int r = 0; r < 4; r++) {
                    float p = exp2f(fminf(sacc[nt][kt][r] * SCL2E, 60.f));
                    lsum[nt] += p;
                    tmp[(kt >> 1) * 8 + (kt & 1) * 4 + r] = __float2bfloat16(p);
                }
            }
            pb[nt][0] = *(const bf16x8*)&tmp[0];
            pb[nt][1] = *(const bf16x8*)&tmp[8];
        }

#pragma unroll
        for (int c = 0; c < 2; c++) {
#pragma unroll
            for (int mt = 0; mt < 8; mt++) {
                int row = mt * 16 + l16;
                int g   = (c * 4 + quad) ^ (l16 & 7);
                bf16x8 av = *(const bf16x8*)&sVc[(size_t)row * BKV + g * 8];
#pragma unroll
                for (int nt = 0; nt < 2; nt++)
                    oacc[nt][mt] = __builtin_amdgcn_mfma_f32_16x16x32_bf16(av, pb[nt][c], oacc[nt][mt], 0, 0, 0);
            }
        }
    }

#pragma unroll
    for (int nt = 0; nt < 2; nt++) {
        float v = lsum[nt];
        v += __shfl_xor(v, 16);
        v += __shfl_xor(v, 32);
        lsum[nt] = v;
    }

#pragma unroll
    for (int nt = 0; nt < 2; nt++) {
        float inv = 1.f / lsum[nt];
        int row = q0 + wave * 32 + nt * 16 + l16;
#pragma unroll
        for (int mt = 0; mt < 8; mt++) {
            bf16 t4[4];
#pragma unroll
            for (int r = 0; r < 4; r++) t4[r] = __float2bfloat16(oacc[nt][mt][r] * inv);
            *(s16x4*)&Op[base + (size_t)row * D_MODEL + mt * 16 + quad * 4] = *(const s16x4*)t4;
        }
    }
}

// ---------------------------------------------------------------------------
extern "C" void kernel_launch(void* const* d_in, const int* in_sizes, int n_in,
                              void* d_out, int out_size, void* d_ws, size_t ws_size,
                              hipStream_t stream)
{
    const float* query  = (const float*)d_in[0];
    const float* key_in = (const float*)d_in[1];
    const float* value  = (const float*)d_in[2];
    const float* Wq = (const float*)d_in[3];
    const float* bq = (const float*)d_in[4];
    const float* Wk = (const float*)d_in[5];
    const float* bk = (const float*)d_in[6];
    const float* Wv = (const float*)d_in[7];
    const float* bv = (const float*)d_in[8];
    const float* Wo = (const float*)d_in[9];
    const float* bo = (const float*)d_in[10];
    float* out = (float*)d_out;

    const int tokens = BATCH * SEQ;                          // 4096
    const size_t nAct = (size_t)tokens * D_MODEL;            // 8.4M elems
    const size_t nW   = (size_t)D_MODEL * D_MODEL;           // 4.2M elems

    const bool fused_qkv = ws_size >= (6 * nAct + 4 * nW) * sizeof(bf16);

    bf16* p = (bf16*)d_ws;
    bf16* qb  = p; p += nAct;      // bf16 activations
    bf16* kb  = p; p += nAct;
    bf16* vb  = p; p += nAct;
    bf16* wqb = p; p += nW;        // bf16 weights
    bf16* wkb = p; p += nW;
    bf16* wvb = p; p += nW;
    bf16* wob = p; p += nW;
    bf16* qp  = p; p += nAct;      // Q,K projections
    bf16* kp  = p; p += nAct;
    bf16* vpT;                     // V projection (transposed+permuted)
    if (fused_qkv) { vpT = p; p += nAct; }
    else           { vpT = qb; }   // fallback: alias (QK launch consumes qb first)
    bf16* ap = fused_qkv ? qb : kb; // attn out: aliases an activation consumed earlier

    // 1. fp32 -> bf16 (one launch)
    CvtArgs ca;
    ca.src[0] = query;  ca.dst[0] = qb;  ca.n8[0] = (int)(nAct / 8);
    ca.src[1] = key_in; ca.dst[1] = kb;  ca.n8[1] = (int)(nAct / 8);
    ca.src[2] = value;  ca.dst[2] = vb;  ca.n8[2] = (int)(nAct / 8);
    ca.src[3] = Wq;     ca.dst[3] = wqb; ca.n8[3] = (int)(nW / 8);
    ca.src[4] = Wk;     ca.dst[4] = wkb; ca.n8[4] = (int)(nW / 8);
    ca.src[5] = Wv;     ca.dst[5] = wvb; ca.n8[5] = (int)(nW / 8);
    ca.src[6] = Wo;     ca.dst[6] = wob; ca.n8[6] = (int)(nW / 8);
    cvt_multi<<<dim3(512, 7), 256, 0, stream>>>(ca);

    // 2. projections: 256x128 tiles -> QKV grid 768 = 3x256 CUs (perfect pack)
    if (fused_qkv) {
        QkvArgs qa;
        qa.A[0] = qb; qa.W[0] = wqb; qa.bias[0] = bq; qa.C[0] = qp;
        qa.A[1] = kb; qa.W[1] = wkb; qa.bias[1] = bk; qa.C[1] = kp;
        qa.A[2] = vb; qa.W[2] = wvb; qa.bias[2] = bv; qa.C[2] = vpT;
        dim3 g3(D_MODEL / 128, tokens / 256, 3);             // (16, 16, 3)
        gemm_qkv<<<g3, 512, 0, stream>>>(qa, tokens, D_MODEL, D_MODEL);
    } else {
        QkArgs qa;
        qa.A[0] = qb; qa.W[0] = wqb; qa.bias[0] = bq; qa.C[0] = qp;
        qa.A[1] = kb; qa.W[1] = wkb; qa.bias[1] = bk; qa.C[1] = kp;
        dim3 g2(D_MODEL / 128, tokens / 256, 2);             // (16, 16, 2)
        gemm_qk<<<g2, 512, 0, stream>>>(qa, tokens, D_MODEL, D_MODEL);
        dim3 gg(D_MODEL / 128, tokens / 256);
        gemm_bf16<bf16, true><<<gg, 512, 0, stream>>>(vb, wvb, bv, vpT, tokens, D_MODEL, D_MODEL);
    }

    // 3. attention
    dim3 ga(SEQ / 128, NUM_HEADS, BATCH);                    // (16, 16, 2)
    flash_attn_kernel<<<ga, 256, 0, stream>>>(qp, kp, vpT, ap);

    // 4. output projection (fp32 out): grid 256 = 1x256 CUs (perfect pack)
    dim3 gg(D_MODEL / 128, tokens / 256);
    gemm_bf16<float, false><<<gg, 512, 0, stream>>>(ap, wob, bo, out, tokens, D_MODEL, D_MODEL);
}